// Round 1
// baseline (588.657 us; speedup 1.0000x reference)
//
#include <hip/hip_runtime.h>

#define BB 16
#define NN 2048
#define DIN 160
#define IS 32          // INPUT_SIZE
#define NC 64          // NUM_CAT
#define EMBD 64        // EMB
#define NCTX (NN - 1)  // 2047
#define NLAYERS 3
#define NT 128         // n-tile for the C reduction

// ---------------- K0: h init -------------------------------------------------
// mid[b][e][n] = sum_c emb[e][c] * x[b][IS+c][n]; tail[b][e][n] = x[b][IS+NC+e][n]
__global__ void k_init(const float* __restrict__ x, const float* __restrict__ emb,
                       float* __restrict__ mid, float* __restrict__ tail) {
    __shared__ float emb_s[EMBD][NC];
    int t = threadIdx.x;
    for (int i = t; i < EMBD * NC; i += 256) emb_s[i >> 6][i & 63] = emb[i];
    __syncthreads();

    int b = blockIdx.y;
    int n = blockIdx.x * 256 + t;
    const float* xb = x + (size_t)b * DIN * NN;

    float acc[EMBD];
#pragma unroll
    for (int e = 0; e < EMBD; e++) acc[e] = 0.f;
    for (int c = 0; c < NC; c++) {
        float xv = xb[(IS + c) * NN + n];
#pragma unroll
        for (int e = 0; e < EMBD; e++) acc[e] += emb_s[e][c] * xv;
    }
    float* midb = mid + (size_t)b * EMBD * NN;
    float* tailb = tail + (size_t)b * EMBD * NN;
#pragma unroll
    for (int e = 0; e < EMBD; e++) {
        midb[e * NN + n] = acc[e];
        tailb[e * NN + n] = xb[(IS + NC + e) * NN + n];
    }
}

// ---------------- K1: C[b][i][d] = sum_{n<NCTX} mid[b][i][n] * x[b][d][n] ----
__global__ void k_reduceC(const float* __restrict__ x, const float* __restrict__ mid,
                          float* __restrict__ C) {
    __shared__ float mid_s[EMBD][NT + 1];  // 33 KB
    __shared__ float xq_s[IS][NT + 1];     // 16.5 KB
    int t = threadIdx.x;
    int b = blockIdx.y;
    int n0 = blockIdx.x * NT;
    const float* xb = x + (size_t)b * DIN * NN;
    const float* midb = mid + (size_t)b * EMBD * NN;

    for (int i = t; i < EMBD * NT; i += 256) {
        int e = i >> 7, n = i & (NT - 1);
        int gn = n0 + n;
        mid_s[e][n] = (gn < NCTX) ? midb[e * NN + gn] : 0.f;
    }
    for (int i = t; i < IS * NT; i += 256) {
        int d = i >> 7, n = i & (NT - 1);
        int gn = n0 + n;
        xq_s[d][n] = (gn < NCTX) ? xb[d * NN + gn] : 0.f;
    }
    __syncthreads();

    int d = t & 31;
    int i0 = (t >> 5) * 8;
    float acc[8];
#pragma unroll
    for (int k = 0; k < 8; k++) acc[k] = 0.f;
    for (int n = 0; n < NT; n++) {
        float xv = xq_s[d][n];
#pragma unroll
        for (int k = 0; k < 8; k++) acc[k] += mid_s[i0 + k][n] * xv;
    }
    float* Cb = C + (size_t)b * EMBD * IS;
#pragma unroll
    for (int k = 0; k < 8; k++) atomicAdd(&Cb[(i0 + k) * IS + d], acc[k]);
}

// ---------------- K2: A = scale*(alpha⊙C)·xq ; mid += M·A ; tail += A -------
__global__ void k_update(const float* __restrict__ x, const float* __restrict__ Cl,
                         const float* __restrict__ alpha_l, const float* __restrict__ kp,
                         const float* __restrict__ Mmat,
                         float* __restrict__ mid, float* __restrict__ tail) {
    __shared__ float W_s[EMBD][IS];    // 8 KB
    __shared__ float M_s[EMBD][EMBD];  // 16 KB
    int t = threadIdx.x;
    int b = blockIdx.y;
    float scale = kp[0] / (float)NCTX;
    const float* Cb = Cl + (size_t)b * EMBD * IS;
    for (int i = t; i < EMBD * IS; i += 256) {
        int e = i >> 5;
        W_s[e][i & 31] = scale * alpha_l[e] * Cb[i];
    }
    for (int i = t; i < EMBD * EMBD; i += 256) M_s[i >> 6][i & 63] = Mmat[i];
    __syncthreads();

    int n = blockIdx.x * 256 + t;
    const float* xb = x + (size_t)b * DIN * NN;
    float xv[IS];
#pragma unroll
    for (int d = 0; d < IS; d++) xv[d] = xb[d * NN + n];

    float A[EMBD];
    for (int i = 0; i < EMBD; i++) {
        float a = 0.f;
#pragma unroll
        for (int d = 0; d < IS; d++) a += W_s[i][d] * xv[d];
        A[i] = a;
    }
    float* midb = mid + (size_t)b * EMBD * NN;
    float* tailb = tail + (size_t)b * EMBD * NN;
    for (int j = 0; j < EMBD; j++) {
        float u = 0.f;
#pragma unroll
        for (int i = 0; i < EMBD; i++) u += M_s[j][i] * A[i];
        midb[j * NN + n] += u;
        tailb[j * NN + n] += A[j];
    }
}

// ---------------- K3: logits = tail^T·emb ; softmax -------------------------
__global__ void k_logits(const float* __restrict__ tail, const float* __restrict__ emb,
                         float* __restrict__ out) {
    __shared__ float emb_s[EMBD][NC];
    int t = threadIdx.x;
    for (int i = t; i < EMBD * NC; i += 256) emb_s[i >> 6][i & 63] = emb[i];
    __syncthreads();

    int b = blockIdx.y;
    int n = blockIdx.x * 256 + t;
    const float* tb = tail + (size_t)b * EMBD * NN;

    float lg[NC];
#pragma unroll
    for (int c = 0; c < NC; c++) lg[c] = 0.f;
    for (int d = 0; d < EMBD; d++) {
        float v = tb[d * NN + n];
#pragma unroll
        for (int c = 0; c < NC; c++) lg[c] += emb_s[d][c] * v;
    }
    float mx = lg[0];
#pragma unroll
    for (int c = 1; c < NC; c++) mx = fmaxf(mx, lg[c]);

    size_t base = ((size_t)b * NN + n) * NC;
    float* lo = out + base;
#pragma unroll
    for (int c = 0; c < NC; c++) lo[c] = lg[c];

    float sum = 0.f;
#pragma unroll
    for (int c = 0; c < NC; c++) {
        lg[c] = __expf(lg[c] - mx);
        sum += lg[c];
    }
    float inv = 1.f / sum;
    float* po = out + (size_t)BB * NN * NC + base;
#pragma unroll
    for (int c = 0; c < NC; c++) po[c] = lg[c] * inv;
}

extern "C" void kernel_launch(void* const* d_in, const int* in_sizes, int n_in,
                              void* d_out, int out_size, void* d_ws, size_t ws_size,
                              hipStream_t stream) {
    const float* x     = (const float*)d_in[0];  // (B, DIN, N)
    const float* alpha = (const float*)d_in[1];  // (3, EMB)
    const float* kp    = (const float*)d_in[2];  // (1,)
    const float* emb   = (const float*)d_in[3];  // (EMB, NC)
    const float* Mmat  = (const float*)d_in[4];  // (EMB, EMB)
    float* out = (float*)d_out;

    float* mid  = (float*)d_ws;                       // B*EMB*N
    float* tail = mid + (size_t)BB * EMBD * NN;       // B*EMB*N
    float* Cbuf = tail + (size_t)BB * EMBD * NN;      // NLAYERS*B*EMB*IS

    hipMemsetAsync(Cbuf, 0, (size_t)NLAYERS * BB * EMBD * IS * sizeof(float), stream);

    dim3 blk(256);
    k_init<<<dim3(NN / 256, BB), blk, 0, stream>>>(x, emb, mid, tail);
    for (int nl = 0; nl < NLAYERS; nl++) {
        float* Cl = Cbuf + (size_t)nl * BB * EMBD * IS;
        k_reduceC<<<dim3(NN / NT, BB), blk, 0, stream>>>(x, mid, Cl);
        k_update<<<dim3(NN / 256, BB), blk, 0, stream>>>(x, Cl, alpha + nl * EMBD, kp,
                                                         Mmat, mid, tail);
    }
    k_logits<<<dim3(NN / 256, BB), blk, 0, stream>>>(tail, emb, out);
}

// Round 2
// 334.998 us; speedup vs baseline: 1.7572x; 1.7572x over previous
//
#include <hip/hip_runtime.h>

#define BB 16
#define NN 2048
#define DIN 160
#define IS 32
#define NCAT 64
#define EMBD 64
#define NCTX 2047
#define CPB 128                    // columns per block
#define NBLK (BB * (NN / CPB))     // 256 blocks -> 1 per CU

// ---------------------------------------------------------------------------
// C-accumulation helper: block-local (i,d) reduction over CPB columns in LDS.
// mid_s[n][e] (pad 68), xq_s[n][d] (pad 36). Thread t -> 4x4 (i,d) tile.
// ---------------------------------------------------------------------------
__device__ __forceinline__ void accum_C(const float (*mid_s)[68], const float (*xq_s)[36],
                                        float* __restrict__ Cb, int t, int nlim) {
    const int ig = t >> 3;   // 0..15 -> i = ig*4 .. +3
    const int dg = t & 7;    // 0..7  -> d = dg*4 .. +3
    float ca00 = 0.f, ca01 = 0.f, ca02 = 0.f, ca03 = 0.f;
    float ca10 = 0.f, ca11 = 0.f, ca12 = 0.f, ca13 = 0.f;
    float ca20 = 0.f, ca21 = 0.f, ca22 = 0.f, ca23 = 0.f;
    float ca30 = 0.f, ca31 = 0.f, ca32 = 0.f, ca33 = 0.f;
    for (int m = 0; m < nlim; m++) {
        float4 mv = *(const float4*)&mid_s[m][ig * 4];
        float4 qv = *(const float4*)&xq_s[m][dg * 4];
        ca00 += mv.x * qv.x; ca01 += mv.x * qv.y; ca02 += mv.x * qv.z; ca03 += mv.x * qv.w;
        ca10 += mv.y * qv.x; ca11 += mv.y * qv.y; ca12 += mv.y * qv.z; ca13 += mv.y * qv.w;
        ca20 += mv.z * qv.x; ca21 += mv.z * qv.y; ca22 += mv.z * qv.z; ca23 += mv.z * qv.w;
        ca30 += mv.w * qv.x; ca31 += mv.w * qv.y; ca32 += mv.w * qv.z; ca33 += mv.w * qv.w;
    }
    float* p0 = Cb + (ig * 4 + 0) * IS + dg * 4;
    float* p1 = Cb + (ig * 4 + 1) * IS + dg * 4;
    float* p2 = Cb + (ig * 4 + 2) * IS + dg * 4;
    float* p3 = Cb + (ig * 4 + 3) * IS + dg * 4;
    atomicAdd(p0 + 0, ca00); atomicAdd(p0 + 1, ca01); atomicAdd(p0 + 2, ca02); atomicAdd(p0 + 3, ca03);
    atomicAdd(p1 + 0, ca10); atomicAdd(p1 + 1, ca11); atomicAdd(p1 + 2, ca12); atomicAdd(p1 + 3, ca13);
    atomicAdd(p2 + 0, ca20); atomicAdd(p2 + 1, ca21); atomicAdd(p2 + 2, ca22); atomicAdd(p2 + 3, ca23);
    atomicAdd(p3 + 0, ca30); atomicAdd(p3 + 1, ca31); atomicAdd(p3 + 2, ca32); atomicAdd(p3 + 3, ca33);
}

// ---------------------------------------------------------------------------
// K0: mid = emb . x_cat  (stored [b][n][e]);  C0 += mid . xq^T (n < 2047)
// ---------------------------------------------------------------------------
__global__ __launch_bounds__(CPB) void k_init(const float* __restrict__ x,
                                              const float* __restrict__ emb,
                                              float* __restrict__ midg,
                                              float* __restrict__ C0) {
    __shared__ float mid_s[CPB][68];
    __shared__ float xq_s[CPB][36];
    const int t = threadIdx.x;
    const int blk = blockIdx.x;
    const int b = blk >> 4;
    const int n = ((blk & 15) << 7) + t;
    const float* xb = x + (size_t)b * DIN * NN;

    // stage xq column into LDS (coalesced global, b128 LDS write)
#pragma unroll
    for (int k = 0; k < 8; k++) {
        float4 v;
        v.x = xb[(k * 4 + 0) * NN + n];
        v.y = xb[(k * 4 + 1) * NN + n];
        v.z = xb[(k * 4 + 2) * NN + n];
        v.w = xb[(k * 4 + 3) * NN + n];
        *(float4*)&xq_s[t][k * 4] = v;
    }
    // categorical slice into registers
    float xc[NCAT];
#pragma unroll
    for (int c = 0; c < NCAT; c++) xc[c] = xb[(IS + c) * NN + n];

    // mid[e] = sum_c emb[e][c] * xc[c]  (emb reads are wave-uniform -> s_load)
    float* mo = midg + ((size_t)b * NN + n) * EMBD;
#pragma unroll 2
    for (int e4 = 0; e4 < EMBD / 4; e4++) {
        float r[4];
#pragma unroll
        for (int j = 0; j < 4; j++) {
            const float* er = emb + (e4 * 4 + j) * NCAT;
            float s = 0.f;
#pragma unroll
            for (int c = 0; c < NCAT; c++) s += er[c] * xc[c];
            r[j] = s;
        }
        float4 v; v.x = r[0]; v.y = r[1]; v.z = r[2]; v.w = r[3];
        *(float4*)(mo + e4 * 4) = v;
        *(float4*)&mid_s[t][e4 * 4] = v;
    }
    __syncthreads();

    const int nlim = ((blk & 15) == 15) ? (CPB - 1) : CPB;
    accum_C(mid_s, xq_s, C0 + (size_t)b * (EMBD * IS), t, nlim);
}

// ---------------------------------------------------------------------------
// K1 (layers 0,1): A = scale*(alpha o Cin) . xq ; mid += M.A ; Asum (+)= A ;
//                  Cout += mid_new . xq^T (n < 2047)
// ---------------------------------------------------------------------------
__global__ __launch_bounds__(CPB) void k_layer(const float* __restrict__ x,
                                               const float* __restrict__ Cin,
                                               const float* __restrict__ alpha_l,
                                               const float* __restrict__ kp,
                                               const float* __restrict__ Mm,
                                               float* __restrict__ midg,
                                               float* __restrict__ asum,
                                               float* __restrict__ Cout,
                                               int first) {
    __shared__ float mid_s[CPB][68];
    __shared__ float xq_s[CPB][36];
    const int t = threadIdx.x;
    const int blk = blockIdx.x;
    const int b = blk >> 4;
    const int n = ((blk & 15) << 7) + t;
    const float* xb = x + (size_t)b * DIN * NN;

    float xq[IS];
#pragma unroll
    for (int d = 0; d < IS; d++) xq[d] = xb[d * NN + n];
#pragma unroll
    for (int k = 0; k < 8; k++) {
        float4 v; v.x = xq[k * 4]; v.y = xq[k * 4 + 1]; v.z = xq[k * 4 + 2]; v.w = xq[k * 4 + 3];
        *(float4*)&xq_s[t][k * 4] = v;
    }

    const float scale = kp[0] * (1.f / (float)NCTX);
    const float* Cb = Cin + (size_t)b * (EMBD * IS);
    float A[EMBD];
#pragma unroll 4
    for (int i = 0; i < EMBD; i++) {
        float s = 0.f;
#pragma unroll
        for (int k = 0; k < 8; k++) {
            float4 cv = *(const float4*)(Cb + i * IS + k * 4);
            s += cv.x * xq[k * 4] + cv.y * xq[k * 4 + 1] + cv.z * xq[k * 4 + 2] + cv.w * xq[k * 4 + 3];
        }
        A[i] = s * (scale * alpha_l[i]);
    }

    // mid column: load, += M.A, store back (global [b][n][e]) + LDS stash
    float* mo = midg + ((size_t)b * NN + n) * EMBD;
    float mr[EMBD];
#pragma unroll
    for (int k = 0; k < 16; k++) {
        float4 v = *(const float4*)(mo + k * 4);
        mr[k * 4] = v.x; mr[k * 4 + 1] = v.y; mr[k * 4 + 2] = v.z; mr[k * 4 + 3] = v.w;
    }
#pragma unroll 4
    for (int j = 0; j < EMBD; j++) {
        const float* Mr = Mm + j * EMBD;
        float u = 0.f;
#pragma unroll
        for (int k = 0; k < 16; k++) {
            float4 mv = *(const float4*)(Mr + k * 4);
            u += mv.x * A[k * 4] + mv.y * A[k * 4 + 1] + mv.z * A[k * 4 + 2] + mv.w * A[k * 4 + 3];
        }
        mr[j] += u;
    }
#pragma unroll
    for (int k = 0; k < 16; k++) {
        float4 v; v.x = mr[k * 4]; v.y = mr[k * 4 + 1]; v.z = mr[k * 4 + 2]; v.w = mr[k * 4 + 3];
        *(float4*)(mo + k * 4) = v;
        *(float4*)&mid_s[t][k * 4] = v;
    }

    // Asum accumulate (A1 (+)= A)
    float* ao = asum + ((size_t)b * NN + n) * EMBD;
    if (first) {
#pragma unroll
        for (int k = 0; k < 16; k++) {
            float4 v; v.x = A[k * 4]; v.y = A[k * 4 + 1]; v.z = A[k * 4 + 2]; v.w = A[k * 4 + 3];
            *(float4*)(ao + k * 4) = v;
        }
    } else {
#pragma unroll
        for (int k = 0; k < 16; k++) {
            float4 v = *(const float4*)(ao + k * 4);
            v.x += A[k * 4]; v.y += A[k * 4 + 1]; v.z += A[k * 4 + 2]; v.w += A[k * 4 + 3];
            *(float4*)(ao + k * 4) = v;
        }
    }
    __syncthreads();

    const int nlim = ((blk & 15) == 15) ? (CPB - 1) : CPB;
    accum_C(mid_s, xq_s, Cout + (size_t)b * (EMBD * IS), t, nlim);
}

// ---------------------------------------------------------------------------
// K2: layer-2 update folded into epilogue: tail = x_tail + Asum + A2 ;
//     logits = tail^T.emb ; softmax -> out
// ---------------------------------------------------------------------------
__global__ __launch_bounds__(CPB) void k_final(const float* __restrict__ x,
                                               const float* __restrict__ Cin,
                                               const float* __restrict__ alpha_l,
                                               const float* __restrict__ kp,
                                               const float* __restrict__ emb,
                                               const float* __restrict__ asum,
                                               float* __restrict__ out) {
    const int t = threadIdx.x;
    const int blk = blockIdx.x;
    const int b = blk >> 4;
    const int n = ((blk & 15) << 7) + t;
    const float* xb = x + (size_t)b * DIN * NN;

    float xq[IS];
#pragma unroll
    for (int d = 0; d < IS; d++) xq[d] = xb[d * NN + n];

    const float scale = kp[0] * (1.f / (float)NCTX);
    const float* Cb = Cin + (size_t)b * (EMBD * IS);
    float A[EMBD];
#pragma unroll 4
    for (int i = 0; i < EMBD; i++) {
        float s = 0.f;
#pragma unroll
        for (int k = 0; k < 8; k++) {
            float4 cv = *(const float4*)(Cb + i * IS + k * 4);
            s += cv.x * xq[k * 4] + cv.y * xq[k * 4 + 1] + cv.z * xq[k * 4 + 2] + cv.w * xq[k * 4 + 3];
        }
        A[i] = s * (scale * alpha_l[i]);
    }

    // tail_final = x_tail + Asum + A
    const float* ao = asum + ((size_t)b * NN + n) * EMBD;
    float tl[EMBD];
#pragma unroll
    for (int k = 0; k < 16; k++) {
        float4 av = *(const float4*)(ao + k * 4);
        tl[k * 4 + 0] = xb[(IS + NCAT + k * 4 + 0) * NN + n] + av.x + A[k * 4 + 0];
        tl[k * 4 + 1] = xb[(IS + NCAT + k * 4 + 1) * NN + n] + av.y + A[k * 4 + 1];
        tl[k * 4 + 2] = xb[(IS + NCAT + k * 4 + 2) * NN + n] + av.z + A[k * 4 + 2];
        tl[k * 4 + 3] = xb[(IS + NCAT + k * 4 + 3) * NN + n] + av.w + A[k * 4 + 3];
    }

    // logits[c] = sum_d tl[d] * emb[d][c]  (emb rows contiguous, wave-uniform)
    float lg[NCAT];
#pragma unroll
    for (int c = 0; c < NCAT; c++) lg[c] = 0.f;
    for (int d = 0; d < EMBD; d++) {
        const float v = tl[d];
        const float* er = emb + d * NCAT;
#pragma unroll
        for (int c = 0; c < NCAT; c++) lg[c] += er[c] * v;
    }

    const size_t base = ((size_t)b * NN + n) * (size_t)NCAT;
    float* lo = out + base;
#pragma unroll
    for (int k = 0; k < 16; k++) {
        float4 v; v.x = lg[k * 4]; v.y = lg[k * 4 + 1]; v.z = lg[k * 4 + 2]; v.w = lg[k * 4 + 3];
        *(float4*)(lo + k * 4) = v;
    }

    float mx = lg[0];
#pragma unroll
    for (int c = 1; c < NCAT; c++) mx = fmaxf(mx, lg[c]);
    float sum = 0.f;
#pragma unroll
    for (int c = 0; c < NCAT; c++) {
        lg[c] = __expf(lg[c] - mx);
        sum += lg[c];
    }
    const float inv = 1.f / sum;
    float* po = out + (size_t)BB * NN * NCAT + base;
#pragma unroll
    for (int k = 0; k < 16; k++) {
        float4 v;
        v.x = lg[k * 4] * inv; v.y = lg[k * 4 + 1] * inv;
        v.z = lg[k * 4 + 2] * inv; v.w = lg[k * 4 + 3] * inv;
        *(float4*)(po + k * 4) = v;
    }
}

extern "C" void kernel_launch(void* const* d_in, const int* in_sizes, int n_in,
                              void* d_out, int out_size, void* d_ws, size_t ws_size,
                              hipStream_t stream) {
    const float* x     = (const float*)d_in[0];
    const float* alpha = (const float*)d_in[1];
    const float* kp    = (const float*)d_in[2];
    const float* emb   = (const float*)d_in[3];
    const float* Mmat  = (const float*)d_in[4];
    float* out = (float*)d_out;

    float* midg = (float*)d_ws;                          // BB*NN*EMBD floats
    float* asum = midg + (size_t)BB * NN * EMBD;         // BB*NN*EMBD floats
    float* Cbuf = asum + (size_t)BB * NN * EMBD;         // 3*BB*EMBD*IS floats
    const size_t csz = (size_t)BB * EMBD * IS;

    hipMemsetAsync(Cbuf, 0, 3 * csz * sizeof(float), stream);

    k_init<<<NBLK, CPB, 0, stream>>>(x, emb, midg, Cbuf);
    k_layer<<<NBLK, CPB, 0, stream>>>(x, Cbuf, alpha, kp, Mmat, midg, asum, Cbuf + csz, 1);
    k_layer<<<NBLK, CPB, 0, stream>>>(x, Cbuf + csz, alpha + EMBD, kp, Mmat, midg, asum,
                                      Cbuf + 2 * csz, 0);
    k_final<<<NBLK, CPB, 0, stream>>>(x, Cbuf + 2 * csz, alpha + 2 * EMBD, kp, emb, asum, out);
}

// Round 4
// 140.037 us; speedup vs baseline: 4.2036x; 2.3922x over previous
//
#include <hip/hip_runtime.h>

#define BB 16
#define NN 2048
#define DIN 160
#define IS 32
#define NCAT 64
#define EMBD 64
#define NCTX 2047

// ---------------------------------------------------------------------------
// K1: per-tile partial G = xq.xq^T (32x32) and K = xcat.xq^T (64x32).
// Grid 256 = 16 b x 16 tiles of 128 columns. Block 256.
// ---------------------------------------------------------------------------
__global__ __launch_bounds__(256) void k_gram(const float* __restrict__ x,
                                              float* __restrict__ Pg,
                                              float* __restrict__ Pk) {
    __shared__ float xs[128][100];  // [n-local][row r<96], pad 100
    const int t = threadIdx.x;
    const int blk = blockIdx.x;
    const int b = blk >> 4;
    const int tile = blk & 15;
    const int n0 = tile << 7;
    const float* xb = x + (size_t)b * DIN * NN;

    // stage rows 0..95 of the 128-column slab (transposed into LDS)
    for (int idx = t; idx < 96 * 32; idx += 256) {
        const int r = idx >> 5;
        const int m4 = (idx & 31) << 2;
        float4 v = *(const float4*)&xb[r * NN + n0 + m4];
        xs[m4 + 0][r] = v.x; xs[m4 + 1][r] = v.y;
        xs[m4 + 2][r] = v.z; xs[m4 + 3][r] = v.w;
    }
    __syncthreads();

    const int nlim = (tile == 15) ? 127 : 128;  // exclude global column 2047
    const int i = t >> 3;          // 0..31
    const int d0 = (t & 7) << 2;   // 0,4,..,28
    float4 g = {0,0,0,0}, k0 = {0,0,0,0}, k1 = {0,0,0,0};
    for (int m = 0; m < nlim; m++) {
        float4 q = *(const float4*)&xs[m][d0];
        const float a  = xs[m][i];        // xq row i
        const float c0 = xs[m][32 + i];   // xcat row i
        const float c1 = xs[m][64 + i];   // xcat row i+32
        g.x  += a  * q.x; g.y  += a  * q.y; g.z  += a  * q.z; g.w  += a  * q.w;
        k0.x += c0 * q.x; k0.y += c0 * q.y; k0.z += c0 * q.z; k0.w += c0 * q.w;
        k1.x += c1 * q.x; k1.y += c1 * q.y; k1.z += c1 * q.z; k1.w += c1 * q.w;
    }
    *(float4*)&Pg[(size_t)blk * 1024 + i * 32 + d0] = g;
    float* pk = Pk + (size_t)blk * 2048;
    *(float4*)&pk[i * 32 + d0] = k0;
    *(float4*)&pk[(i + 32) * 32 + d0] = k1;
}

// ---------------------------------------------------------------------------
// K2: per-batch tiny matrix chain. Grid 16, block 256.
// reduce partials -> G (32x32), K (64x32); C0 = emb.K;
// for l: W += scale*diag(a_l)*C;  C += M.(scale*diag(a_l)*C.G)  (l<2)
// U = emb^T.W  -> Ubuf[b]
// Thread owns row r = t>>2, cols dd..dd+7 (dd = (t&3)*8).
// ---------------------------------------------------------------------------
__global__ __launch_bounds__(256) void k_chain(const float* __restrict__ Pg,
                                               const float* __restrict__ Pk,
                                               const float* __restrict__ alpha,
                                               const float* __restrict__ kp,
                                               const float* __restrict__ emb,
                                               const float* __restrict__ Mm,
                                               float* __restrict__ Ubuf) {
    __shared__ float G_s[32][36];
    __shared__ float K_s[64][36];
    __shared__ float C_s[64][36];
    __shared__ float W_s[64][36];
    __shared__ float T_s[64][36];
    const int t = threadIdx.x;
    const int b = blockIdx.x;

    for (int idx = t; idx < 1024; idx += 256) {
        float s = 0.f;
#pragma unroll
        for (int g = 0; g < 16; g++) s += Pg[((size_t)(b * 16 + g)) * 1024 + idx];
        G_s[idx >> 5][idx & 31] = s;
    }
    for (int idx = t; idx < 2048; idx += 256) {
        float s = 0.f;
#pragma unroll
        for (int g = 0; g < 16; g++) s += Pk[((size_t)(b * 16 + g)) * 2048 + idx];
        K_s[idx >> 5][idx & 31] = s;
    }
    __syncthreads();

    const int r  = t >> 2;         // 0..63
    const int dd = (t & 3) << 3;   // 0,8,16,24

    // C0 = emb . K
    {
        const float* er = emb + r * EMBD;
        float acc[8];
#pragma unroll
        for (int j = 0; j < 8; j++) acc[j] = 0.f;
        for (int c = 0; c < 64; c++) {
            const float e = er[c];
#pragma unroll
            for (int j = 0; j < 8; j++) acc[j] += e * K_s[c][dd + j];
        }
#pragma unroll
        for (int j = 0; j < 8; j++) C_s[r][dd + j] = acc[j];
    }
    __syncthreads();

    const float scale = kp[0] * (1.f / (float)NCTX);
    for (int l = 0; l < 3; l++) {
        const float f = scale * alpha[l * EMBD + r];
#pragma unroll
        for (int j = 0; j < 8; j++) {
            const float w = f * C_s[r][dd + j];
            if (l == 0) W_s[r][dd + j] = w; else W_s[r][dd + j] += w;
        }
        if (l < 2) {
            float crow[32];
#pragma unroll
            for (int d = 0; d < 32; d++) crow[d] = C_s[r][d];
            float tacc[8];
#pragma unroll
            for (int j = 0; j < 8; j++) tacc[j] = 0.f;
            for (int d = 0; d < 32; d++) {
                const float cv = crow[d];
#pragma unroll
                for (int j = 0; j < 8; j++) tacc[j] += cv * G_s[d][dd + j];
            }
#pragma unroll
            for (int j = 0; j < 8; j++) T_s[r][dd + j] = f * tacc[j];
            __syncthreads();
            const float* Mr = Mm + r * EMBD;
            float uacc[8];
#pragma unroll
            for (int j = 0; j < 8; j++) uacc[j] = 0.f;
            for (int jj = 0; jj < 64; jj++) {
                const float mv = Mr[jj];
#pragma unroll
                for (int j = 0; j < 8; j++) uacc[j] += mv * T_s[jj][dd + j];
            }
#pragma unroll
            for (int j = 0; j < 8; j++) C_s[r][dd + j] += uacc[j];
            __syncthreads();
        }
    }
    __syncthreads();

    // U[c][d] = sum_e emb[e][c] * W[e][d], c = r
    {
        float acc[8];
#pragma unroll
        for (int j = 0; j < 8; j++) acc[j] = 0.f;
        for (int e = 0; e < 64; e++) {
            const float ev = emb[e * EMBD + r];
#pragma unroll
            for (int j = 0; j < 8; j++) acc[j] += ev * W_s[e][dd + j];
        }
        float* Ur = Ubuf + (size_t)b * 2048 + r * 32 + dd;
#pragma unroll
        for (int j = 0; j < 8; j++) Ur[j] = acc[j];
    }
}

// ---------------------------------------------------------------------------
// K3: logits[:,n] = emb^T.x_tail[:,n] + U.xq[:,n]; softmax.
// Grid 256 = 16 b x 16 tiles; block 256: t = h*128+nl, h = c-half.
// ---------------------------------------------------------------------------
__global__ __launch_bounds__(256) void k_out(const float* __restrict__ x,
                                             const float* __restrict__ emb,
                                             const float* __restrict__ Ubuf,
                                             float* __restrict__ out) {
    __shared__ float lg_s[128][68];
    const int t = threadIdx.x;
    const int blk = blockIdx.x;
    const int b = blk >> 4;
    const int tile = blk & 15;
    const int h = t >> 7;
    const int nl = t & 127;
    const int n = (tile << 7) + nl;
    const int c0 = h << 5;
    const float* xb = x + (size_t)b * DIN * NN;

    float xq[IS];
#pragma unroll
    for (int d = 0; d < IS; d++) xq[d] = xb[d * NN + n];

    // U half: rows c0..c0+31 (wave-uniform rows -> scalar loads)
    float lg[32];
    const float* Ub = Ubuf + (size_t)b * 2048;
#pragma unroll 4
    for (int cl = 0; cl < 32; cl++) {
        const float* Ur = Ub + (c0 + cl) * 32;
        float s = 0.f;
#pragma unroll
        for (int k = 0; k < 8; k++) {
            float4 u = *(const float4*)&Ur[4 * k];
            s += u.x * xq[4*k] + u.y * xq[4*k+1] + u.z * xq[4*k+2] + u.w * xq[4*k+3];
        }
        lg[cl] = s;
    }
    // + emb^T . x_tail
    for (int e = 0; e < 64; e++) {
        const float tv = xb[(IS + NCAT + e) * NN + n];
        const float* er = emb + e * EMBD + c0;  // wave-uniform
#pragma unroll
        for (int cl = 0; cl < 32; cl++) lg[cl] += er[cl] * tv;
    }

    const size_t base = ((size_t)b * NN + n) * (size_t)NCAT;
    float* lo = out + base + c0;
#pragma unroll
    for (int k = 0; k < 8; k++) {
        float4 v = {lg[4*k], lg[4*k+1], lg[4*k+2], lg[4*k+3]};
        *(float4*)&lo[4*k] = v;
        *(float4*)&lg_s[nl][c0 + 4*k] = v;
    }
    __syncthreads();

    const int o0 = (1 - h) << 5;
    float mx = lg[0];
#pragma unroll
    for (int cl = 1; cl < 32; cl++) mx = fmaxf(mx, lg[cl]);
    float og[32];
#pragma unroll
    for (int k = 0; k < 8; k++) {
        float4 v = *(const float4*)&lg_s[nl][o0 + 4*k];
        og[4*k] = v.x; og[4*k+1] = v.y; og[4*k+2] = v.z; og[4*k+3] = v.w;
    }
#pragma unroll
    for (int cl = 0; cl < 32; cl++) mx = fmaxf(mx, og[cl]);

    float sum = 0.f;
#pragma unroll
    for (int cl = 0; cl < 32; cl++) {
        lg[cl] = __expf(lg[cl] - mx);
        sum += lg[cl];
    }
#pragma unroll
    for (int cl = 0; cl < 32; cl++) sum += __expf(og[cl] - mx);

    const float inv = 1.f / sum;
    float* po = out + (size_t)BB * NN * NCAT + base + c0;
#pragma unroll
    for (int k = 0; k < 8; k++) {
        float4 v = {lg[4*k]*inv, lg[4*k+1]*inv, lg[4*k+2]*inv, lg[4*k+3]*inv};
        *(float4*)&po[4*k] = v;
    }
}

extern "C" void kernel_launch(void* const* d_in, const int* in_sizes, int n_in,
                              void* d_out, int out_size, void* d_ws, size_t ws_size,
                              hipStream_t stream) {
    const float* x     = (const float*)d_in[0];
    const float* alpha = (const float*)d_in[1];
    const float* kp    = (const float*)d_in[2];
    const float* emb   = (const float*)d_in[3];
    const float* Mmat  = (const float*)d_in[4];
    float* out = (float*)d_out;

    float* Pg   = (float*)d_ws;                    // 256*1024
    float* Pk   = Pg + (size_t)256 * 1024;         // 256*2048
    float* Ubuf = Pk + (size_t)256 * 2048;         // 16*2048

    k_gram <<<256, 256, 0, stream>>>(x, Pg, Pk);
    k_chain<<<16,  256, 0, stream>>>(Pg, Pk, alpha, kp, emb, Mmat, Ubuf);
    k_out  <<<256, 256, 0, stream>>>(x, emb, Ubuf, out);
}